// Round 5
// baseline (148.159 us; speedup 1.0000x reference)
//
#include <hip/hip_runtime.h>
#include <hip/hip_bf16.h>
#include <math.h>

constexpr int kB = 128;
constexpr int kT = 256;
constexpr int kC = 384;
constexpr int kH = 64;

using bf16x8 = __attribute__((ext_vector_type(8))) short;  // 8 bf16 = 4 VGPRs
using f32x4  = __attribute__((ext_vector_type(4))) float;

union BF8 { bf16x8 v; __hip_bfloat162 h[4]; };

__device__ inline bf16x8 cvt8(float4 a, float4 b) {
    BF8 u;
    u.h[0] = __float22bfloat162_rn(float2{a.x, a.y});
    u.h[1] = __float22bfloat162_rn(float2{a.z, a.w});
    u.h[2] = __float22bfloat162_rn(float2{b.x, b.y});
    u.h[3] = __float22bfloat162_rn(float2{b.z, b.w});
    return u.v;
}

// ---------------------------------------------------------------------------
// Kernel 0: Wt[n][k] bf16, n in [0,192) = (w*64+h), k in [0,384).
// Wk rows pre-scaled by 384^-0.5 (k only feeds scores).
// ---------------------------------------------------------------------------
__global__ void prep_kernel(const float* __restrict__ Wq,
                            const float* __restrict__ Wk,
                            const float* __restrict__ Wv,
                            __hip_bfloat16* __restrict__ Wt) {
    int idx = blockIdx.x * 256 + threadIdx.x;     // [0, 192*384)
    int n = idx / kC, c = idx % kC;
    int w = n >> 6, h = n & 63;
    const float* W = (w == 0) ? Wq : (w == 1) ? Wk : Wv;
    float val = W[c * kH + h];
    if (w == 1) val *= 0.051031036307982884f;     // 384^-0.5
    Wt[idx] = __float2bfloat16(val);
}

// ---------------------------------------------------------------------------
// Kernel 1: QKV GEMM, MFMA 16x16x32 bf16. Wave = 16 rows x 192 cols.
// n-OUTER / k-INNER: A-frags (full K strip) converted to bf16 registers once;
// per n-tile j all 12 B-frags load into a register array (12 loads in flight)
// while the previous tile's 12-deep MFMA acc chain executes -> B-load latency
// hidden (this chain was the ~50 us invariant of rounds 2-4).
// ---------------------------------------------------------------------------
__global__ __launch_bounds__(256) void qkv_kernel(
    const float* __restrict__ x, const __hip_bfloat16* __restrict__ Wt,
    __hip_bfloat16* __restrict__ q, __hip_bfloat16* __restrict__ k,
    __hip_bfloat16* __restrict__ vT)
{
    const int tid  = threadIdx.x;
    const int wave = tid >> 6, lane = tid & 63;
    const int m16  = lane & 15, quad = lane >> 4;
    const int rowA = blockIdx.x * 64 + wave * 16 + m16;

    const float* xa = x + (size_t)rowA * kC + quad * 8;
    const short* wt = (const short*)Wt;

    // entire K=384 strip as bf16 A-frags (48 VGPRs)
    bf16x8 af[12];
#pragma unroll
    for (int c = 0; c < 12; ++c) {
        float4 a0 = *(const float4*)(xa + 32 * c);
        float4 a1 = *(const float4*)(xa + 32 * c + 4);
        af[c] = cvt8(a0, a1);
    }

    f32x4 acc[12];
#pragma unroll
    for (int j = 0; j < 12; ++j) acc[j] = f32x4{0.f, 0.f, 0.f, 0.f};

#pragma unroll
    for (int j = 0; j < 12; ++j) {
        const short* wrow = wt + (size_t)(j * 16 + m16) * kC + quad * 8;
        bf16x8 bfr[12];
#pragma unroll
        for (int kk = 0; kk < 12; ++kk)
            bfr[kk] = *(const bf16x8*)(wrow + 32 * kk);
#pragma unroll
        for (int kk = 0; kk < 12; ++kk)
            acc[j] = __builtin_amdgcn_mfma_f32_16x16x32_bf16(af[kk], bfr[kk], acc[j], 0, 0, 0);
    }

    // epilogue: C-layout col = m16 (within n-tile), row = quad*4 + r
    const int rbase = blockIdx.x * 64 + wave * 16 + quad * 4;
#pragma unroll
    for (int j = 0; j < 12; ++j) {
        const int w = j >> 2;
        const int h = (j & 3) * 16 + m16;
#pragma unroll
        for (int r = 0; r < 4; ++r) {
            const int m = rbase + r;
            __hip_bfloat16 val = __float2bfloat16(acc[j][r]);
            if (w == 0)      q[(size_t)m * kH + h] = val;
            else if (w == 1) k[(size_t)m * kH + h] = val;
            else             vT[((size_t)(m >> 8) * kH + h) * kT + (m & 255)] = val;
        }
    }
}

// ---------------------------------------------------------------------------
// Kernel 2: flash attention, split-KV. Block = 4 waves = 2 bands x 2 s-halves.
// Wave (band, shalf) handles t-band [tb,tb+16), s-chunks s0 = shalf*32 step 64.
// v B-frags hoisted above softmax (independent of it) so their latency hides
// under the exp/shuffle chain. Partials merged across band waves via LDS.
// ---------------------------------------------------------------------------
__global__ __launch_bounds__(256) void attn_kernel(
    const __hip_bfloat16* __restrict__ qg, const __hip_bfloat16* __restrict__ kg,
    const __hip_bfloat16* __restrict__ vTg, float* __restrict__ out)
{
    __shared__ float Pb[4][16 * 33];    // per-wave P round-trip
    __shared__ float Mb[2][64 * 25];    // per-band merge: {m[4], l[4], O[16]}/lane

    const int b    = blockIdx.y;
    const int g    = 7 - blockIdx.x;        // heavy bands dispatch first
    const int tid  = threadIdx.x;
    const int wave = tid >> 6, lane = tid & 63;
    const int band = wave >> 1, shalf = wave & 1;
    const int m16  = lane & 15, quad = lane >> 4;
    const int tb   = g * 32 + band * 16;

    const short* qs = (const short*)qg + (size_t)b * kT * kH;
    const short* ks = (const short*)kg + (size_t)b * kT * kH;
    const short* vs = (const short*)vTg + (size_t)b * kH * kT;

    // K A-frags for this band (pre-scaled by 384^-0.5 via Wt)
    const bf16x8 ka0 = *(const bf16x8*)(ks + (size_t)(tb + m16) * kH + quad * 8);
    const bf16x8 ka1 = *(const bf16x8*)(ks + (size_t)(tb + m16) * kH + quad * 8 + 32);

    f32x4 O[4];
    float m_[4], l_[4];
#pragma unroll
    for (int i = 0; i < 4; ++i) {
        O[i] = f32x4{0.f, 0.f, 0.f, 0.f};
        m_[i] = -INFINITY; l_[i] = 0.f;
    }
    float* Pw = &Pb[wave][0];

    for (int s0 = shalf * 32; s0 < tb + 16; s0 += 64) {
        const short* qb = qs + (size_t)(s0 + m16) * kH + quad * 8;
        bf16x8 q00 = *(const bf16x8*)(qb);
        bf16x8 q01 = *(const bf16x8*)(qb + 32);
        bf16x8 q10 = *(const bf16x8*)(qb + 16 * kH);
        bf16x8 q11 = *(const bf16x8*)(qb + 16 * kH + 32);

        // v B-frags: independent of softmax, issue now
        bf16x8 vf[4];
#pragma unroll
        for (int ht = 0; ht < 4; ++ht)
            vf[ht] = *(const bf16x8*)(vs + (size_t)(ht * 16 + m16) * kT + s0 + quad * 8);

        const f32x4 Z = f32x4{0.f, 0.f, 0.f, 0.f};
        f32x4 S0 = __builtin_amdgcn_mfma_f32_16x16x32_bf16(ka0, q00, Z, 0, 0, 0);
        S0       = __builtin_amdgcn_mfma_f32_16x16x32_bf16(ka1, q01, S0, 0, 0, 0);
        f32x4 S1 = __builtin_amdgcn_mfma_f32_16x16x32_bf16(ka0, q10, Z, 0, 0, 0);
        S1       = __builtin_amdgcn_mfma_f32_16x16x32_bf16(ka1, q11, S1, 0, 0, 0);

        if (s0 + 32 > tb) {   // diagonal-crossing chunk: causal mask
#pragma unroll
            for (int r = 0; r < 4; ++r) {
                const int trow = tb + quad * 4 + r;
                if (s0 + m16      > trow) S0[r] = -INFINITY;
                if (s0 + 16 + m16 > trow) S1[r] = -INFINITY;
            }
        }

        float P0[4], P1[4];
#pragma unroll
        for (int r = 0; r < 4; ++r) {
            float rm = fmaxf(S0[r], S1[r]);
            rm = fmaxf(rm, __shfl_xor(rm, 1, 64));
            rm = fmaxf(rm, __shfl_xor(rm, 2, 64));
            rm = fmaxf(rm, __shfl_xor(rm, 4, 64));
            rm = fmaxf(rm, __shfl_xor(rm, 8, 64));
            const float mn = fmaxf(m_[r], rm);
            const float al = __expf(m_[r] - mn);
            m_[r] = mn;
            P0[r] = __expf(S0[r] - mn);
            P1[r] = __expf(S1[r] - mn);
            float rs = P0[r] + P1[r];
            rs += __shfl_xor(rs, 1, 64);
            rs += __shfl_xor(rs, 2, 64);
            rs += __shfl_xor(rs, 4, 64);
            rs += __shfl_xor(rs, 8, 64);
            l_[r] = l_[r] * al + rs;
            O[0][r] *= al; O[1][r] *= al; O[2][r] *= al; O[3][r] *= al;
        }

        // P round-trip: C-layout write, A-layout read (stride 33: 2-way max)
#pragma unroll
        for (int r = 0; r < 4; ++r) {
            Pw[(quad * 4 + r) * 33 + m16]      = P0[r];
            Pw[(quad * 4 + r) * 33 + m16 + 16] = P1[r];
        }
        const float* pr = Pw + m16 * 33 + quad * 8;
        float4 pa = make_float4(pr[0], pr[1], pr[2], pr[3]);
        float4 pc = make_float4(pr[4], pr[5], pr[6], pr[7]);
        bf16x8 pf = cvt8(pa, pc);

#pragma unroll
        for (int ht = 0; ht < 4; ++ht)
            O[ht] = __builtin_amdgcn_mfma_f32_16x16x32_bf16(pf, vf[ht], O[ht], 0, 0, 0);
    }

    // merge the two s-halves of each band
    if (shalf == 1) {
        float* dst = &Mb[band][lane * 25];
#pragma unroll
        for (int r = 0; r < 4; ++r) { dst[r] = m_[r]; dst[4 + r] = l_[r]; }
#pragma unroll
        for (int ht = 0; ht < 4; ++ht)
#pragma unroll
            for (int r = 0; r < 4; ++r) dst[8 + ht * 4 + r] = O[ht][r];
    }
    __syncthreads();
    if (shalf == 0) {
        const float* src = &Mb[band][lane * 25];
#pragma unroll
        for (int r = 0; r < 4; ++r) {
            const float m1 = src[r], l1 = src[4 + r];
            const float mm = fmaxf(m_[r], m1);
            const float a0 = __expf(m_[r] - mm);
            const float a1 = __expf(m1 - mm);
            const float inv = 1.f / (l_[r] * a0 + l1 * a1);
            const size_t row = (size_t)(b * kT + tb + quad * 4 + r);
#pragma unroll
            for (int ht = 0; ht < 4; ++ht)
                out[row * kH + ht * 16 + m16] =
                    (O[ht][r] * a0 + src[8 + ht * 4 + r] * a1) * inv;
        }
    }
}

// ---------------------------------------------------------------------------
extern "C" void kernel_launch(void* const* d_in, const int* in_sizes, int n_in,
                              void* d_out, int out_size, void* d_ws, size_t ws_size,
                              hipStream_t stream) {
    const float* x  = (const float*)d_in[0];
    const float* Wq = (const float*)d_in[1];
    const float* Wk = (const float*)d_in[2];
    const float* Wv = (const float*)d_in[3];
    float* out = (float*)d_out;

    const size_t nqkv = (size_t)kB * kT * kH;           // 2 M elems
    __hip_bfloat16* q  = (__hip_bfloat16*)d_ws;         // 4 MB
    __hip_bfloat16* k  = q + nqkv;                      // 4 MB
    __hip_bfloat16* vT = k + nqkv;                      // 4 MB [b][h][s]
    __hip_bfloat16* Wt = vT + nqkv;                     // 147 KB [n][k]

    prep_kernel<<<(192 * kC) / 256, 256, 0, stream>>>(Wq, Wk, Wv, Wt);
    qkv_kernel<<<(kB * kT) / 64, 256, 0, stream>>>(x, Wt, q, k, vT);
    attn_kernel<<<dim3(8, kB), 256, 0, stream>>>(q, k, vT, out);
}

// Round 6
// 119.293 us; speedup vs baseline: 1.2420x; 1.2420x over previous
//
#include <hip/hip_runtime.h>
#include <hip/hip_bf16.h>
#include <math.h>

constexpr int kB = 128;
constexpr int kT = 256;
constexpr int kC = 384;
constexpr int kH = 64;

using bf16x8 = __attribute__((ext_vector_type(8))) short;  // 8 bf16 = 4 VGPRs
using f32x4  = __attribute__((ext_vector_type(4))) float;

union BF8 { bf16x8 v; __hip_bfloat162 h[4]; };
union BF4 { short4 s; __hip_bfloat162 h[2]; };

__device__ inline bf16x8 cvt8(float4 a, float4 b) {
    BF8 u;
    u.h[0] = __float22bfloat162_rn(float2{a.x, a.y});
    u.h[1] = __float22bfloat162_rn(float2{a.z, a.w});
    u.h[2] = __float22bfloat162_rn(float2{b.x, b.y});
    u.h[3] = __float22bfloat162_rn(float2{b.z, b.w});
    return u.v;
}
__device__ inline short4 cvt4(float4 a) {
    BF4 u;
    u.h[0] = __float22bfloat162_rn(float2{a.x, a.y});
    u.h[1] = __float22bfloat162_rn(float2{a.z, a.w});
    return u.s;
}

// ---------------------------------------------------------------------------
// Kernel 0: Wt[n][k] bf16, n in [0,192) = (w*64+h), k in [0,384).
// Wk rows pre-scaled by 384^-0.5 (k only feeds scores).
// ---------------------------------------------------------------------------
__global__ void prep_kernel(const float* __restrict__ Wq,
                            const float* __restrict__ Wk,
                            const float* __restrict__ Wv,
                            __hip_bfloat16* __restrict__ Wt) {
    int idx = blockIdx.x * 256 + threadIdx.x;     // [0, 192*384)
    int n = idx / kC, c = idx % kC;
    int w = n >> 6, h = n & 63;
    const float* W = (w == 0) ? Wq : (w == 1) ? Wk : Wv;
    float val = W[c * kH + h];
    if (w == 1) val *= 0.051031036307982884f;     // 384^-0.5
    Wt[idx] = __float2bfloat16(val);
}

// ---------------------------------------------------------------------------
// Kernel 1: QKV GEMM, LDS double-buffered (m97 pattern). Block: M=64, N=192,
// BK=32, 512 threads. Waves 0-3 stage x (fp32->bf16), waves 4-7 stage Wt.
// All 8 waves compute: wave=(wm=wave&1 -> 32-row half, wn=wave>>1 -> 48-col
// slice), 2x3 16x16 tiles. LDS strides 40 bf16 (pad 8): 2-way max = free.
// Grid 512 = 2 blocks/CU -> barrier stalls overlap across blocks.
// ---------------------------------------------------------------------------
__global__ __launch_bounds__(512) void qkv_kernel(
    const float* __restrict__ x, const __hip_bfloat16* __restrict__ Wt,
    __hip_bfloat16* __restrict__ q, __hip_bfloat16* __restrict__ k,
    __hip_bfloat16* __restrict__ vT)
{
    __shared__ short As[2][64 * 40];    // [m][kk] bf16, stride 40
    __shared__ short Bs[2][192 * 40];   // [n][kk] bf16, stride 40

    const int tid  = threadIdx.x;
    const int wave = tid >> 6, lane = tid & 63;
    const int m16  = lane & 15, quad = lane >> 4;
    const int wm = wave & 1, wn = wave >> 1;
    const int m0 = blockIdx.x * 64;
    const short* wt = (const short*)Wt;

    // staging descriptors (role is wave-uniform: waves 0-3 = A, 4-7 = B)
    const bool stageA = (tid < 256);
    int ar0 = 0, ao0 = 0, ar1 = 0, ao1 = 0;
    int br[3] = {0, 0, 0}, bo[3] = {0, 0, 0};
    if (stageA) {
        ar0 = tid >> 3;        ao0 = (tid & 7) * 4;      // fp32 col offset
        ar1 = (tid >> 3) + 32; ao1 = ao0;
    } else {
        const int u = tid - 256;
#pragma unroll
        for (int i = 0; i < 3; ++i) {
            int c = u + i * 256;
            br[i] = c >> 2; bo[i] = (c & 3) * 8;          // bf16 col offset
        }
    }

    float4 la0, la1; bf16x8 lb[3];
    auto glod = [&](int k0) {
        if (stageA) {
            la0 = *(const float4*)(x + (size_t)(m0 + ar0) * kC + k0 + ao0);
            la1 = *(const float4*)(x + (size_t)(m0 + ar1) * kC + k0 + ao1);
        } else {
#pragma unroll
            for (int i = 0; i < 3; ++i)
                lb[i] = *(const bf16x8*)(wt + (size_t)br[i] * kC + k0 + bo[i]);
        }
    };
    auto swr = [&](int d) {
        if (stageA) {
            *(short4*)&As[d][ar0 * 40 + ao0] = cvt4(la0);
            *(short4*)&As[d][ar1 * 40 + ao1] = cvt4(la1);
        } else {
#pragma unroll
            for (int i = 0; i < 3; ++i)
                *(bf16x8*)&Bs[d][br[i] * 40 + bo[i]] = lb[i];
        }
    };

    f32x4 acc[2][3];
#pragma unroll
    for (int mt = 0; mt < 2; ++mt)
#pragma unroll
        for (int j = 0; j < 3; ++j) acc[mt][j] = f32x4{0.f, 0.f, 0.f, 0.f};

    glod(0);
    swr(0);
    __syncthreads();

    for (int s = 0; s < 12; ++s) {
        const int d = s & 1;
        if (s < 11) glod((s + 1) * 32);   // in flight during compute

        bf16x8 af[2], bfr[3];
#pragma unroll
        for (int mt = 0; mt < 2; ++mt)
            af[mt] = *(const bf16x8*)&As[d][(wm * 32 + mt * 16 + m16) * 40 + quad * 8];
#pragma unroll
        for (int j = 0; j < 3; ++j)
            bfr[j] = *(const bf16x8*)&Bs[d][(wn * 48 + j * 16 + m16) * 40 + quad * 8];
#pragma unroll
        for (int mt = 0; mt < 2; ++mt)
#pragma unroll
            for (int j = 0; j < 3; ++j)
                acc[mt][j] = __builtin_amdgcn_mfma_f32_16x16x32_bf16(
                    af[mt], bfr[j], acc[mt][j], 0, 0, 0);

        if (s < 11) swr(d ^ 1);
        __syncthreads();
    }

    // epilogue: C-layout col=m16 (in-tile), row=quad*4+r; n-tiles never
    // straddle the 64-col q/k/v boundary (bases are multiples of 16).
#pragma unroll
    for (int mt = 0; mt < 2; ++mt) {
#pragma unroll
        for (int j = 0; j < 3; ++j) {
            const int n = wn * 48 + j * 16 + m16;
            const int w = n >> 6, h = n & 63;
#pragma unroll
            for (int r = 0; r < 4; ++r) {
                const int m = m0 + wm * 32 + mt * 16 + quad * 4 + r;
                __hip_bfloat16 val = __float2bfloat16(acc[mt][j][r]);
                if (w == 0)      q[(size_t)m * kH + h] = val;
                else if (w == 1) k[(size_t)m * kH + h] = val;
                else             vT[((size_t)(m >> 8) * kH + h) * kT + (m & 255)] = val;
            }
        }
    }
}

// ---------------------------------------------------------------------------
// Kernel 2: flash attention, block-cooperative LDS staging. Block = (b, tq):
// t-rows [tq*64, tq*64+64), 4 waves (wave = 16-row band). k A-frags in regs.
// q-tile/vT-tile (64x64 bf16, stride 72) double-buffered; chunk count tq+1 is
// block-uniform. Diagonal chunk: band w computes n-tiles j<=w, tile j==w
// masked, stale P cols zeroed. P round-trip per wave (f32, stride 68).
// ---------------------------------------------------------------------------
__global__ __launch_bounds__(256) void attn_kernel(
    const __hip_bfloat16* __restrict__ qg, const __hip_bfloat16* __restrict__ kg,
    const __hip_bfloat16* __restrict__ vTg, float* __restrict__ out)
{
    __shared__ short Qs[2][64 * 72];    // [s][h]
    __shared__ short Vs[2][64 * 72];    // [h][s]
    __shared__ float Ps[4][16 * 68];    // per-wave P round-trip

    const int b  = blockIdx.y;
    const int tq = blockIdx.x;
    const int tid  = threadIdx.x;
    const int wave = tid >> 6, lane = tid & 63;
    const int m16  = lane & 15, quad = lane >> 4;
    const int tband = tq * 64 + wave * 16;

    const short* qs = (const short*)qg + (size_t)b * kT * kH;
    const short* ks = (const short*)kg + (size_t)b * kT * kH;
    const short* vs = (const short*)vTg + (size_t)b * kH * kT;

    // K A-frags for this band (k pre-scaled by 384^-0.5 via Wt)
    const bf16x8 ka0 = *(const bf16x8*)(ks + (size_t)(tband + m16) * kH + quad * 8);
    const bf16x8 ka1 = *(const bf16x8*)(ks + (size_t)(tband + m16) * kH + quad * 8 + 32);

    // staging: thread covers rows r0 and r0+32, one 8-bf16 segment each
    const int r0 = tid >> 3, sg = (tid & 7) * 8;

    bf16x8 lq0, lq1, lv0, lv1;
    auto glod = [&](int sc) {
        lq0 = *(const bf16x8*)(qs + (size_t)(sc + r0) * kH + sg);
        lq1 = *(const bf16x8*)(qs + (size_t)(sc + r0 + 32) * kH + sg);
        lv0 = *(const bf16x8*)(vs + (size_t)r0 * kT + sc + sg);
        lv1 = *(const bf16x8*)(vs + (size_t)(r0 + 32) * kT + sc + sg);
    };
    auto swr = [&](int d) {
        *(bf16x8*)&Qs[d][r0 * 72 + sg]        = lq0;
        *(bf16x8*)&Qs[d][(r0 + 32) * 72 + sg] = lq1;
        *(bf16x8*)&Vs[d][r0 * 72 + sg]        = lv0;
        *(bf16x8*)&Vs[d][(r0 + 32) * 72 + sg] = lv1;
    };

    f32x4 O[4];
    float m_[4], l_[4];
#pragma unroll
    for (int i = 0; i < 4; ++i) {
        O[i] = f32x4{0.f, 0.f, 0.f, 0.f};
        m_[i] = -INFINITY; l_[i] = 0.f;
    }
    float* Pw = &Ps[wave][0];

    glod(0);
    swr(0);
    __syncthreads();

    for (int i = 0; i <= tq; ++i) {
        const int d = i & 1;
        if (i < tq) glod((i + 1) * 64);

        const int jmax = (i == tq) ? wave : 3;   // wave-uniform

        // S = k-band @ q-chunk^T : n-tiles j (16 s-cols each), K=64 (h)
        f32x4 S[4];
        const f32x4 Z = f32x4{0.f, 0.f, 0.f, 0.f};
#pragma unroll
        for (int j = 0; j < 4; ++j) {
            if (j <= jmax) {
                bf16x8 qb0 = *(const bf16x8*)&Qs[d][(j * 16 + m16) * 72 + quad * 8];
                bf16x8 qb1 = *(const bf16x8*)&Qs[d][(j * 16 + m16) * 72 + 32 + quad * 8];
                S[j] = __builtin_amdgcn_mfma_f32_16x16x32_bf16(ka0, qb0, Z, 0, 0, 0);
                S[j] = __builtin_amdgcn_mfma_f32_16x16x32_bf16(ka1, qb1, S[j], 0, 0, 0);
            }
        }
        if (i == tq) {   // only the j==wave tile straddles the diagonal
#pragma unroll
            for (int r = 0; r < 4; ++r)
                if (m16 > quad * 4 + r) S[wave][r] = -INFINITY;
        }

        // online softmax per row r (rows quad*4+r; stats across m16 group)
        float P[4][4];
#pragma unroll
        for (int j = 0; j < 4; ++j)
#pragma unroll
            for (int r = 0; r < 4; ++r) P[j][r] = 0.f;
#pragma unroll
        for (int r = 0; r < 4; ++r) {
            float rm = -INFINITY;
#pragma unroll
            for (int j = 0; j < 4; ++j)
                if (j <= jmax) rm = fmaxf(rm, S[j][r]);
            rm = fmaxf(rm, __shfl_xor(rm, 1, 64));
            rm = fmaxf(rm, __shfl_xor(rm, 2, 64));
            rm = fmaxf(rm, __shfl_xor(rm, 4, 64));
            rm = fmaxf(rm, __shfl_xor(rm, 8, 64));
            const float mn = fmaxf(m_[r], rm);
            const float al = __expf(m_[r] - mn);
            m_[r] = mn;
            float rs = 0.f;
#pragma unroll
            for (int j = 0; j < 4; ++j) {
                if (j <= jmax) { P[j][r] = __expf(S[j][r] - mn); rs += P[j][r]; }
            }
            rs += __shfl_xor(rs, 1, 64);
            rs += __shfl_xor(rs, 2, 64);
            rs += __shfl_xor(rs, 4, 64);
            rs += __shfl_xor(rs, 8, 64);
            l_[r] = l_[r] * al + rs;
            O[0][r] *= al; O[1][r] *= al; O[2][r] *= al; O[3][r] *= al;
        }

        // P: C-layout write (zeros for j>jmax kill stale cols), A-layout read
#pragma unroll
        for (int j = 0; j < 4; ++j)
#pragma unroll
            for (int r = 0; r < 4; ++r)
                Pw[(quad * 4 + r) * 68 + j * 16 + m16] = P[j][r];
        const float* pr = Pw + m16 * 68 + quad * 8;
        bf16x8 pf0 = cvt8(*(const float4*)pr,        *(const float4*)(pr + 4));
        bf16x8 pf1 = cvt8(*(const float4*)(pr + 32), *(const float4*)(pr + 36));

        // O += P @ V
#pragma unroll
        for (int ht = 0; ht < 4; ++ht) {
            bf16x8 vb0 = *(const bf16x8*)&Vs[d][(ht * 16 + m16) * 72 + quad * 8];
            bf16x8 vb1 = *(const bf16x8*)&Vs[d][(ht * 16 + m16) * 72 + 32 + quad * 8];
            O[ht] = __builtin_amdgcn_mfma_f32_16x16x32_bf16(pf0, vb0, O[ht], 0, 0, 0);
            O[ht] = __builtin_amdgcn_mfma_f32_16x16x32_bf16(pf1, vb1, O[ht], 0, 0, 0);
        }

        if (i < tq) swr(d ^ 1);
        __syncthreads();
    }

    // epilogue
#pragma unroll
    for (int r = 0; r < 4; ++r) {
        const float inv = 1.f / l_[r];
        const size_t row = (size_t)(b * kT + tband + quad * 4 + r);
#pragma unroll
        for (int ht = 0; ht < 4; ++ht)
            out[row * kH + ht * 16 + m16] = O[ht][r] * inv;
    }
}

// ---------------------------------------------------------------------------
extern "C" void kernel_launch(void* const* d_in, const int* in_sizes, int n_in,
                              void* d_out, int out_size, void* d_ws, size_t ws_size,
                              hipStream_t stream) {
    const float* x  = (const float*)d_in[0];
    const float* Wq = (const float*)d_in[1];
    const float* Wk = (const float*)d_in[2];
    const float* Wv = (const float*)d_in[3];
    float* out = (float*)d_out;

    const size_t nqkv = (size_t)kB * kT * kH;           // 2 M elems
    __hip_bfloat16* q  = (__hip_bfloat16*)d_ws;         // 4 MB
    __hip_bfloat16* k  = q + nqkv;                      // 4 MB
    __hip_bfloat16* vT = k + nqkv;                      // 4 MB [b][h][s]
    __hip_bfloat16* Wt = vT + nqkv;                     // 147 KB [n][k]

    prep_kernel<<<(192 * kC) / 256, 256, 0, stream>>>(Wq, Wk, Wv, Wt);
    qkv_kernel<<<(kB * kT) / 64, 512, 0, stream>>>(x, Wt, q, k, vT);
    attn_kernel<<<dim3(4, kB), 256, 0, stream>>>(q, k, vT, out);
}

// Round 7
// 117.450 us; speedup vs baseline: 1.2615x; 1.0157x over previous
//
#include <hip/hip_runtime.h>
#include <hip/hip_bf16.h>
#include <math.h>

constexpr int kB = 128;
constexpr int kT = 256;
constexpr int kC = 384;
constexpr int kH = 64;

using bf16x8 = __attribute__((ext_vector_type(8))) short;  // 8 bf16 = 4 VGPRs
using f32x4  = __attribute__((ext_vector_type(4))) float;

union BF8 { bf16x8 v; __hip_bfloat162 h[4]; };
union BF4 { short4 s; __hip_bfloat162 h[2]; };

__device__ inline bf16x8 cvt8(float4 a, float4 b) {
    BF8 u;
    u.h[0] = __float22bfloat162_rn(float2{a.x, a.y});
    u.h[1] = __float22bfloat162_rn(float2{a.z, a.w});
    u.h[2] = __float22bfloat162_rn(float2{b.x, b.y});
    u.h[3] = __float22bfloat162_rn(float2{b.z, b.w});
    return u.v;
}
__device__ inline short4 cvt4(float4 a) {
    BF4 u;
    u.h[0] = __float22bfloat162_rn(float2{a.x, a.y});
    u.h[1] = __float22bfloat162_rn(float2{a.z, a.w});
    return u.s;
}

// ---------------------------------------------------------------------------
// Kernel 0: Wt[n][k] bf16, n in [0,192) = (w*64+h), k in [0,384).
// Wk rows pre-scaled by 384^-0.5 (k only feeds scores).
// ---------------------------------------------------------------------------
__global__ void prep_kernel(const float* __restrict__ Wq,
                            const float* __restrict__ Wk,
                            const float* __restrict__ Wv,
                            __hip_bfloat16* __restrict__ Wt) {
    int idx = blockIdx.x * 256 + threadIdx.x;     // [0, 192*384)
    int n = idx / kC, c = idx % kC;
    int w = n >> 6, h = n & 63;
    const float* W = (w == 0) ? Wq : (w == 1) ? Wk : Wv;
    float val = W[c * kH + h];
    if (w == 1) val *= 0.051031036307982884f;     // 384^-0.5
    Wt[idx] = __float2bfloat16(val);
}

// ---------------------------------------------------------------------------
// Kernel 1: QKV GEMM, LDS double-buffered. Block: M=64, N=192, BK=64 (6 steps
// -> half the barrier drains of BK=32), 512 threads. Waves 0-3 stage x
// (fp32->bf16), waves 4-7 stage Wt. Each wave computes 2x3 16x16 tiles with
// 12 MFMA per K-step. LDS strides 72 bf16: 2-way max = free. LDS 73.7 KB ->
// exactly 2 blocks/CU; __launch_bounds__(512,4) caps VGPR at 128 to keep it.
// ---------------------------------------------------------------------------
__global__ __launch_bounds__(512, 4) void qkv_kernel(
    const float* __restrict__ x, const __hip_bfloat16* __restrict__ Wt,
    __hip_bfloat16* __restrict__ q, __hip_bfloat16* __restrict__ k,
    __hip_bfloat16* __restrict__ vT)
{
    __shared__ short As[2][64 * 72];    // [m][kk] bf16, stride 72
    __shared__ short Bs[2][192 * 72];   // [n][kk] bf16, stride 72

    const int tid  = threadIdx.x;
    const int wave = tid >> 6, lane = tid & 63;
    const int m16  = lane & 15, quad = lane >> 4;
    const int wm = wave & 1, wn = wave >> 1;
    const int m0 = blockIdx.x * 64;
    const short* wt = (const short*)Wt;

    // staging descriptors (role wave-uniform: waves 0-3 = A, 4-7 = B)
    const bool stageA = (tid < 256);
    const int am  = tid >> 2;             // A: x row
    const int ak0 = (tid & 3) * 16;       // A: 16-col fp32 chunk
    const int bu  = tid - 256;            // B: chunk base

    float4 la[4]; bf16x8 lb[6];
    auto glod = [&](int k0) {
        if (stageA) {
#pragma unroll
            for (int i = 0; i < 4; ++i)
                la[i] = *(const float4*)(x + (size_t)(m0 + am) * kC + k0 + ak0 + 4 * i);
        } else {
#pragma unroll
            for (int i = 0; i < 6; ++i) {
                int c = bu + 256 * i;             // [0,1536)
                int n = c >> 3, kk = (c & 7) * 8;
                lb[i] = *(const bf16x8*)(wt + (size_t)n * kC + k0 + kk);
            }
        }
    };
    auto swr = [&](int d) {
        if (stageA) {
#pragma unroll
            for (int i = 0; i < 4; ++i)
                *(short4*)&As[d][am * 72 + ak0 + 4 * i] = cvt4(la[i]);
        } else {
#pragma unroll
            for (int i = 0; i < 6; ++i) {
                int c = bu + 256 * i;
                int n = c >> 3, kk = (c & 7) * 8;
                *(bf16x8*)&Bs[d][n * 72 + kk] = lb[i];
            }
        }
    };

    f32x4 acc[2][3];
#pragma unroll
    for (int mt = 0; mt < 2; ++mt)
#pragma unroll
        for (int j = 0; j < 3; ++j) acc[mt][j] = f32x4{0.f, 0.f, 0.f, 0.f};

    glod(0);
    swr(0);
    __syncthreads();

    for (int s = 0; s < 6; ++s) {
        const int d = s & 1;
        if (s < 5) glod((s + 1) * 64);   // next tile in flight during compute

#pragma unroll
        for (int kf = 0; kf < 2; ++kf) {
            bf16x8 af[2], bfr[3];
#pragma unroll
            for (int mt = 0; mt < 2; ++mt)
                af[mt] = *(const bf16x8*)&As[d][(wm * 32 + mt * 16 + m16) * 72 + kf * 32 + quad * 8];
#pragma unroll
            for (int j = 0; j < 3; ++j)
                bfr[j] = *(const bf16x8*)&Bs[d][(wn * 48 + j * 16 + m16) * 72 + kf * 32 + quad * 8];
#pragma unroll
            for (int mt = 0; mt < 2; ++mt)
#pragma unroll
                for (int j = 0; j < 3; ++j)
                    acc[mt][j] = __builtin_amdgcn_mfma_f32_16x16x32_bf16(
                        af[mt], bfr[j], acc[mt][j], 0, 0, 0);
        }

        if (s < 5) swr(d ^ 1);
        __syncthreads();
    }

    // epilogue: C-layout col=m16 (in-tile), row=quad*4+r; n-tiles never
    // straddle the 64-col q/k/v boundary (bases are multiples of 16).
#pragma unroll
    for (int mt = 0; mt < 2; ++mt) {
#pragma unroll
        for (int j = 0; j < 3; ++j) {
            const int n = wn * 48 + j * 16 + m16;
            const int w = n >> 6, h = n & 63;
#pragma unroll
            for (int r = 0; r < 4; ++r) {
                const int m = m0 + wm * 32 + mt * 16 + quad * 4 + r;
                __hip_bfloat16 val = __float2bfloat16(acc[mt][j][r]);
                if (w == 0)      q[(size_t)m * kH + h] = val;
                else if (w == 1) k[(size_t)m * kH + h] = val;
                else             vT[((size_t)(m >> 8) * kH + h) * kT + (m & 255)] = val;
            }
        }
    }
}

// ---------------------------------------------------------------------------
// Kernel 2: flash attention, block-cooperative LDS staging. Block = (b, tq):
// t-rows [tq*64, tq*64+64), 4 waves (wave = 16-row band). k A-frags in regs.
// q-tile/vT-tile (64x64 bf16, stride 72) double-buffered; chunk count tq+1 is
// block-uniform. Diagonal chunk: band w computes n-tiles j<=w, tile j==w
// masked, stale P cols zeroed. P round-trip per wave (f32, stride 68).
// ---------------------------------------------------------------------------
__global__ __launch_bounds__(256) void attn_kernel(
    const __hip_bfloat16* __restrict__ qg, const __hip_bfloat16* __restrict__ kg,
    const __hip_bfloat16* __restrict__ vTg, float* __restrict__ out)
{
    __shared__ short Qs[2][64 * 72];    // [s][h]
    __shared__ short Vs[2][64 * 72];    // [h][s]
    __shared__ float Ps[4][16 * 68];    // per-wave P round-trip

    const int b  = blockIdx.y;
    const int tq = blockIdx.x;
    const int tid  = threadIdx.x;
    const int wave = tid >> 6, lane = tid & 63;
    const int m16  = lane & 15, quad = lane >> 4;
    const int tband = tq * 64 + wave * 16;

    const short* qs = (const short*)qg + (size_t)b * kT * kH;
    const short* ks = (const short*)kg + (size_t)b * kT * kH;
    const short* vs = (const short*)vTg + (size_t)b * kH * kT;

    // K A-frags for this band (k pre-scaled by 384^-0.5 via Wt)
    const bf16x8 ka0 = *(const bf16x8*)(ks + (size_t)(tband + m16) * kH + quad * 8);
    const bf16x8 ka1 = *(const bf16x8*)(ks + (size_t)(tband + m16) * kH + quad * 8 + 32);

    // staging: thread covers rows r0 and r0+32, one 8-bf16 segment each
    const int r0 = tid >> 3, sg = (tid & 7) * 8;

    bf16x8 lq0, lq1, lv0, lv1;
    auto glod = [&](int sc) {
        lq0 = *(const bf16x8*)(qs + (size_t)(sc + r0) * kH + sg);
        lq1 = *(const bf16x8*)(qs + (size_t)(sc + r0 + 32) * kH + sg);
        lv0 = *(const bf16x8*)(vs + (size_t)r0 * kT + sc + sg);
        lv1 = *(const bf16x8*)(vs + (size_t)(r0 + 32) * kT + sc + sg);
    };
    auto swr = [&](int d) {
        *(bf16x8*)&Qs[d][r0 * 72 + sg]        = lq0;
        *(bf16x8*)&Qs[d][(r0 + 32) * 72 + sg] = lq1;
        *(bf16x8*)&Vs[d][r0 * 72 + sg]        = lv0;
        *(bf16x8*)&Vs[d][(r0 + 32) * 72 + sg] = lv1;
    };

    f32x4 O[4];
    float m_[4], l_[4];
#pragma unroll
    for (int i = 0; i < 4; ++i) {
        O[i] = f32x4{0.f, 0.f, 0.f, 0.f};
        m_[i] = -INFINITY; l_[i] = 0.f;
    }
    float* Pw = &Ps[wave][0];

    glod(0);
    swr(0);
    __syncthreads();

    for (int i = 0; i <= tq; ++i) {
        const int d = i & 1;
        if (i < tq) glod((i + 1) * 64);

        const int jmax = (i == tq) ? wave : 3;   // wave-uniform

        // S = k-band @ q-chunk^T : n-tiles j (16 s-cols each), K=64 (h)
        f32x4 S[4];
        const f32x4 Z = f32x4{0.f, 0.f, 0.f, 0.f};
#pragma unroll
        for (int j = 0; j < 4; ++j) {
            if (j <= jmax) {
                bf16x8 qb0 = *(const bf16x8*)&Qs[d][(j * 16 + m16) * 72 + quad * 8];
                bf16x8 qb1 = *(const bf16x8*)&Qs[d][(j * 16 + m16) * 72 + 32 + quad * 8];
                S[j] = __builtin_amdgcn_mfma_f32_16x16x32_bf16(ka0, qb0, Z, 0, 0, 0);
                S[j] = __builtin_amdgcn_mfma_f32_16x16x32_bf16(ka1, qb1, S[j], 0, 0, 0);
            }
        }
        if (i == tq) {   // only the j==wave tile straddles the diagonal
#pragma unroll
            for (int r = 0; r < 4; ++r)
                if (m16 > quad * 4 + r) S[wave][r] = -INFINITY;
        }

        // online softmax per row r (rows quad*4+r; stats across m16 group)
        float P[4][4];
#pragma unroll
        for (int j = 0; j < 4; ++j)
#pragma unroll
            for (int r = 0; r < 4; ++r) P[j][r] = 0.f;
#pragma unroll
        for (int r = 0; r < 4; ++r) {
            float rm = -INFINITY;
#pragma unroll
            for (int j = 0; j < 4; ++j)
                if (j <= jmax) rm = fmaxf(rm, S[j][r]);
            rm = fmaxf(rm, __shfl_xor(rm, 1, 64));
            rm = fmaxf(rm, __shfl_xor(rm, 2, 64));
            rm = fmaxf(rm, __shfl_xor(rm, 4, 64));
            rm = fmaxf(rm, __shfl_xor(rm, 8, 64));
            const float mn = fmaxf(m_[r], rm);
            const float al = __expf(m_[r] - mn);
            m_[r] = mn;
            float rs = 0.f;
#pragma unroll
            for (int j = 0; j < 4; ++j) {
                if (j <= jmax) { P[j][r] = __expf(S[j][r] - mn); rs += P[j][r]; }
            }
            rs += __shfl_xor(rs, 1, 64);
            rs += __shfl_xor(rs, 2, 64);
            rs += __shfl_xor(rs, 4, 64);
            rs += __shfl_xor(rs, 8, 64);
            l_[r] = l_[r] * al + rs;
            O[0][r] *= al; O[1][r] *= al; O[2][r] *= al; O[3][r] *= al;
        }

        // P: C-layout write (zeros for j>jmax kill stale cols), A-layout read
#pragma unroll
        for (int j = 0; j < 4; ++j)
#pragma unroll
            for (int r = 0; r < 4; ++r)
                Pw[(quad * 4 + r) * 68 + j * 16 + m16] = P[j][r];
        const float* pr = Pw + m16 * 68 + quad * 8;
        bf16x8 pf0 = cvt8(*(const float4*)pr,        *(const float4*)(pr + 4));
        bf16x8 pf1 = cvt8(*(const float4*)(pr + 32), *(const float4*)(pr + 36));

        // O += P @ V
#pragma unroll
        for (int ht = 0; ht < 4; ++ht) {
            bf16x8 vb0 = *(const bf16x8*)&Vs[d][(ht * 16 + m16) * 72 + quad * 8];
            bf16x8 vb1 = *(const bf16x8*)&Vs[d][(ht * 16 + m16) * 72 + 32 + quad * 8];
            O[ht] = __builtin_amdgcn_mfma_f32_16x16x32_bf16(pf0, vb0, O[ht], 0, 0, 0);
            O[ht] = __builtin_amdgcn_mfma_f32_16x16x32_bf16(pf1, vb1, O[ht], 0, 0, 0);
        }

        if (i < tq) swr(d ^ 1);
        __syncthreads();
    }

    // epilogue
#pragma unroll
    for (int r = 0; r < 4; ++r) {
        const float inv = 1.f / l_[r];
        const size_t row = (size_t)(b * kT + tband + quad * 4 + r);
#pragma unroll
        for (int ht = 0; ht < 4; ++ht)
            out[row * kH + ht * 16 + m16] = O[ht][r] * inv;
    }
}

// ---------------------------------------------------------------------------
extern "C" void kernel_launch(void* const* d_in, const int* in_sizes, int n_in,
                              void* d_out, int out_size, void* d_ws, size_t ws_size,
                              hipStream_t stream) {
    const float* x  = (const float*)d_in[0];
    const float* Wq = (const float*)d_in[1];
    const float* Wk = (const float*)d_in[2];
    const float* Wv = (const float*)d_in[3];
    float* out = (float*)d_out;

    const size_t nqkv = (size_t)kB * kT * kH;           // 2 M elems
    __hip_bfloat16* q  = (__hip_bfloat16*)d_ws;         // 4 MB
    __hip_bfloat16* k  = q + nqkv;                      // 4 MB
    __hip_bfloat16* vT = k + nqkv;                      // 4 MB [b][h][s]
    __hip_bfloat16* Wt = vT + nqkv;                     // 147 KB [n][k]

    prep_kernel<<<(192 * kC) / 256, 256, 0, stream>>>(Wq, Wk, Wv, Wt);
    qkv_kernel<<<(kB * kT) / 64, 512, 0, stream>>>(x, Wt, q, k, vT);
    attn_kernel<<<dim3(4, kB), 256, 0, stream>>>(q, k, vT, out);
}